// Round 4
// baseline (723.881 us; speedup 1.0000x reference)
//
#include <hip/hip_runtime.h>
#include <hip/hip_bf16.h>

typedef __bf16 bf16x8 __attribute__((ext_vector_type(8)));
typedef __bf16 bf16x4 __attribute__((ext_vector_type(4)));
typedef float  f32x4  __attribute__((ext_vector_type(4)));

#define DEVI __device__ __forceinline__

DEVI float bf2f(__hip_bfloat16 x) { return __bfloat162float(x); }
DEVI __hip_bfloat16 f2bf(float x) { return __float2bfloat16(x); }

DEVI f32x4 mfma16(bf16x8 a, bf16x8 b, f32x4 c) {
    return __builtin_amdgcn_mfma_f32_16x16x32_bf16(a, b, c, 0, 0, 0);
}

DEVI bf16x8 ld8(const __hip_bfloat16* p) {       // 16B-aligned
    return *reinterpret_cast<const bf16x8*>(p);
}
DEVI bf16x8 ld8b(const __hip_bfloat16* p) {      // 8B-aligned (2x ds_read_b64)
    bf16x4 lo = *reinterpret_cast<const bf16x4*>(p);
    bf16x4 hi = *reinterpret_cast<const bf16x4*>(p + 4);
    bf16x8 r;
#pragma unroll
    for (int i = 0; i < 4; ++i) { r[i] = lo[i]; r[i + 4] = hi[i]; }
    return r;
}
DEVI bf16x8 cvt8(const float* p) {
    bf16x8 r;
#pragma unroll
    for (int i = 0; i < 8; ++i) r[i] = (__bf16)p[i];
    return r;
}

// ---------------------------------------------------------------------------
// Sizes: B=64, N=256, D=128, H=8, DK=16, FF=512.  All external I/O fp32.
// st row stride: 20 bf16 (40 B) -> row-start bank = nm*10 mod 32 (16 banks).
// ---------------------------------------------------------------------------

// K0: repack fp32 weights into MFMA-B-friendly bf16 layouts + zero the LN stats
__global__ __launch_bounds__(256) void repack_kernel(
    const float* __restrict__ Wq, const float* __restrict__ Wk,
    const float* __restrict__ Wv, const float* __restrict__ W_out,
    const float* __restrict__ ff_w1, const float* __restrict__ ff_w2,
    __hip_bfloat16* __restrict__ Wqkvt, __hip_bfloat16* __restrict__ Wot,
    __hip_bfloat16* __restrict__ w1t, __hip_bfloat16* __restrict__ w2t,
    float* __restrict__ stats)
{
    int t = blockIdx.x * 256 + threadIdx.x;
    if (t < 256) stats[t] = 0.f;           // statsA[128] + statsB[128]
    if (t < 49152) {                       // Wqkvt[c][d], c = qkv*128 + h*16 + k
        int c = t >> 7, d = t & 127;
        int qkv = c >> 7, h = (c >> 4) & 7, k = c & 15;
        const float* W = (qkv == 0) ? Wq : (qkv == 1) ? Wk : Wv;
        Wqkvt[t] = f2bf(W[(h * 128 + d) * 16 + k]);
    } else if (t < 65536) {                // Wot[d][h*16+v] = W_out[h][v][d]
        int idx = t - 49152;
        int d = idx >> 7, hv = idx & 127, h = hv >> 4, v = hv & 15;
        Wot[idx] = f2bf(W_out[(h * 16 + v) * 128 + d]);
    } else if (t < 131072) {               // w1t[f][d] = ff_w1[d][f]
        int idx = t - 65536;
        int f = idx >> 7, d = idx & 127;
        w1t[idx] = f2bf(ff_w1[d * 512 + f]);
    } else {                               // w2t[d2][f] = ff_w2[f][d2]
        int idx = t - 131072;
        int d2 = idx >> 9, f = idx & 511;
        w2t[idx] = f2bf(ff_w2[f * 128 + d2]);
    }
}

// K1: QKV projection -> Q [b][h][n][k], K [b][h][m][k], Vt [b][h][k][m]
__global__ __launch_bounds__(512) void qkv_kernel(
    const float* __restrict__ hem, const __hip_bfloat16* __restrict__ Wqkvt,
    __hip_bfloat16* __restrict__ Qb, __hip_bfloat16* __restrict__ Kb,
    __hip_bfloat16* __restrict__ Vtb)
{
    const int w = threadIdx.x >> 6, lane = threadIdx.x & 63;
    const int quad = lane >> 4, col = lane & 15;
    const int row0 = blockIdx.x * 32;

    f32x4 acc[2][3] = {};
#pragma unroll
    for (int ks = 0; ks < 4; ++ks) {
        bf16x8 a[2], bb[3];
#pragma unroll
        for (int mt = 0; mt < 2; ++mt)
            a[mt] = cvt8(hem + (size_t)(row0 + mt * 16 + col) * 128 + ks * 32 + quad * 8);
#pragma unroll
        for (int nt = 0; nt < 3; ++nt) {
            int c = (w * 3 + nt) * 16 + col;
            bb[nt] = ld8(Wqkvt + (size_t)c * 128 + ks * 32 + quad * 8);
        }
#pragma unroll
        for (int mt = 0; mt < 2; ++mt)
#pragma unroll
            for (int nt = 0; nt < 3; ++nt)
                acc[mt][nt] = mfma16(a[mt], bb[nt], acc[mt][nt]);
    }
#pragma unroll
    for (int mt = 0; mt < 2; ++mt)
#pragma unroll
        for (int nt = 0; nt < 3; ++nt)
#pragma unroll
            for (int rg = 0; rg < 4; ++rg) {
                int row = row0 + mt * 16 + quad * 4 + rg;
                int c = (w * 3 + nt) * 16 + col;
                int qkv = c >> 7, h = (c >> 4) & 7, k = c & 15;
                int bb_ = row >> 8, n = row & 255;
                __hip_bfloat16 v = f2bf(acc[mt][nt][rg]);
                if (qkv == 0)      Qb[(((size_t)bb_ * 8 + h) * 256 + n) * 16 + k] = v;
                else if (qkv == 1) Kb[(((size_t)bb_ * 8 + h) * 256 + n) * 16 + k] = v;
                else               Vtb[(((size_t)bb_ * 8 + h) * 16 + k) * 256 + n] = v;
            }
}

// K2: fused attention. One block = (b, 4 rows). 512 threads = 8 waves.
__global__ __launch_bounds__(512) void attn_kernel_v2(
    const __hip_bfloat16* __restrict__ Qb, const __hip_bfloat16* __restrict__ Kb,
    const __hip_bfloat16* __restrict__ Vtb, const float* __restrict__ route,
    const float* __restrict__ sa_w1, const float* __restrict__ sa_b1,
    const float* __restrict__ sa_w2, const float* __restrict__ sa_b2,
    const float* __restrict__ h_em, const __hip_bfloat16* __restrict__ Wot,
    float* __restrict__ y, float* __restrict__ out, float* __restrict__ statsA)
{
    // arena: st 40960 | softb 16896 | headsb 4352 | saw1t 1024 | saw2t 1024 | biases 128
    __shared__ alignas(16) char arena[64384];
    __hip_bfloat16* st     = (__hip_bfloat16*)arena;            // [1024][20] bf16
    float*          stf    = (float*)arena;                     // f32 view: [1024][10], ch<8
    __hip_bfloat16* softb  = (__hip_bfloat16*)(arena + 40960);  // [8][4][264]
    __hip_bfloat16* headsb = (__hip_bfloat16*)(arena + 57856);  // [16][136]
    __hip_bfloat16* saw1t  = (__hip_bfloat16*)(arena + 62208);  // [16][32]
    __hip_bfloat16* saw2t  = (__hip_bfloat16*)(arena + 63232);  // [16][32]
    float*          b1s    = (float*)(arena + 64256);
    float*          b2s    = (float*)(arena + 64320);

    const int tid = threadIdx.x;
    const int w = tid >> 6, lane = tid & 63, quad = lane >> 4, col = lane & 15;
    const int b = blockIdx.x >> 6, tile = blockIdx.x & 63, n0 = tile * 4;
    const f32x4 zero = {0.f, 0.f, 0.f, 0.f};

    {   // P0: stage score_aggr weights (transposed, zero-padded to K=32)
        int o = tid >> 5, i = tid & 31;
        saw1t[o * 32 + i] = (i < 16) ? f2bf(sa_w1[i * 16 + o]) : f2bf(0.f);
        saw2t[o * 32 + i] = (i < 16 && o < 8) ? f2bf(sa_w2[i * 8 + o]) : f2bf(0.f);
        if (tid < 16) {
            b1s[tid] = sa_b1[tid];
            b2s[tid] = (tid < 8) ? sa_b2[tid] : 0.f;
        }
    }

    {   // P1: scores (wave w <-> head h=w) + route staging + route passthrough copy
        const int h = w;
        const __hip_bfloat16* Qh = Qb + ((size_t)(b * 8 + h)) * 256 * 16;
        const __hip_bfloat16* Kh = Kb + ((size_t)(b * 8 + h)) * 256 * 16;
        bf16x8 aq = ld8(Qh + (size_t)(n0 + (col & 3)) * 16 + (quad & 1) * 8);
#pragma unroll
        for (int nt = 0; nt < 16; ++nt) {
            bf16x8 bk = {};
            if (quad < 2) bk = ld8(Kh + (size_t)(nt * 16 + col) * 16 + quad * 8);
            f32x4 c = mfma16(aq, bk, zero);
            if (quad == 0) {
#pragma unroll
                for (int rg = 0; rg < 4; ++rg)
                    st[(rg * 256 + nt * 16 + col) * 20 + h] = f2bf(c[rg]);
            }
        }
        const size_t rbase = (((size_t)h * 64 + b) * 256 + n0) * 256;
        const float* rsrc = route + rbase;
        float* rdst = out + 2097152 + rbase;
#pragma unroll
        for (int j = 0; j < 4; ++j)
#pragma unroll
            for (int r = 0; r < 4; ++r) {
                int nm = r * 256 + j * 64 + lane;   // lane-stride-1: 4-way not 64-way
                float v = rsrc[nm];
                rdst[nm] = v;
                st[nm * 20 + 8 + h] = f2bf(v);
            }
    }
    __syncthreads();

    {   // P2: score_aggr (2x MFMA over channel dim; tiles wave-private; f32 out in-place)
        bf16x8 bw1 = ld8(&saw1t[col * 32 + quad * 8]);
        bf16x8 bw2 = ld8(&saw2t[col * 32 + quad * 8]);
        float bias1 = b1s[col], bias2 = b2s[col];
#pragma unroll
        for (int t8 = 0; t8 < 8; ++t8) {
            int nm0 = (w * 8 + t8) * 16;
            bf16x8 a = ld8b(&st[(nm0 + col) * 20 + (quad & 1) * 8]);
            f32x4 h1 = mfma16(a, bw1, zero);
#pragma unroll
            for (int rg = 0; rg < 4; ++rg) {
                int nm = nm0 + quad * 4 + rg;
                st[nm * 20 + col] = f2bf(fmaxf(h1[rg] + bias1, 0.f));
            }
            __asm__ volatile("s_waitcnt lgkmcnt(0)" ::: "memory");
            bf16x8 a2 = ld8b(&st[(nm0 + col) * 20 + (quad & 1) * 8]);
            f32x4 h2 = mfma16(a2, bw2, zero);
            if (col < 8) {
#pragma unroll
                for (int rg = 0; rg < 4; ++rg) {
                    int nm = nm0 + quad * 4 + rg;
                    stf[nm * 10 + col] = h2[rg] + bias2;
                }
            }
            __asm__ volatile("s_waitcnt lgkmcnt(0)" ::: "memory");
        }
    }
    __syncthreads();

    {   // P3: softmax over m for each (h, r); write soft bf16 to softb
#pragma unroll
        for (int pp = 0; pp < 4; ++pp) {
            int p = w * 4 + pp, h = p >> 2, r = p & 3;
            float vv[4];
#pragma unroll
            for (int j = 0; j < 4; ++j) vv[j] = stf[(r * 256 + j * 64 + lane) * 10 + h];
            float mx = fmaxf(fmaxf(vv[0], vv[1]), fmaxf(vv[2], vv[3]));
#pragma unroll
            for (int off = 32; off; off >>= 1) mx = fmaxf(mx, __shfl_xor(mx, off, 64));
            float e[4], s = 0.f;
#pragma unroll
            for (int j = 0; j < 4; ++j) { e[j] = __expf(vv[j] - mx); s += e[j]; }
#pragma unroll
            for (int off = 32; off; off >>= 1) s += __shfl_xor(s, off, 64);
            float inv = 1.f / s;
#pragma unroll
            for (int j = 0; j < 4; ++j)
                softb[(h * 4 + r) * 264 + j * 64 + lane] = f2bf(e[j] * inv);
        }
    }
    __syncthreads();

    {   // P4: PV (wave w <-> head h=w)
        const int h = w;
        f32x4 acc = zero;
        const __hip_bfloat16* Vh = Vtb + ((size_t)(b * 8 + h)) * 16 * 256;
#pragma unroll
        for (int ks = 0; ks < 8; ++ks) {
            bf16x8 a = ld8(&softb[(h * 4 + (col & 3)) * 264 + ks * 32 + quad * 8]);
            bf16x8 bv = ld8(Vh + (size_t)col * 256 + ks * 32 + quad * 8);
            acc = mfma16(a, bv, acc);
        }
        if (quad == 0) {
#pragma unroll
            for (int rg = 0; rg < 4; ++rg)
                headsb[rg * 136 + h * 16 + col] = f2bf(acc[rg]);
        }
    }
    __syncthreads();

    {   // P5: out-proj + residual -> y (fp32) + per-batch LN stats
        f32x4 acc = zero;
#pragma unroll
        for (int ks = 0; ks < 4; ++ks) {
            bf16x8 a = ld8(&headsb[col * 136 + ks * 32 + quad * 8]);
            bf16x8 bo = ld8(Wot + (size_t)(w * 16 + col) * 128 + ks * 32 + quad * 8);
            acc = mfma16(a, bo, acc);
        }
        float s1 = 0.f, s2 = 0.f;
        if (quad == 0) {
#pragma unroll
            for (int rg = 0; rg < 4; ++rg) {
                int n = n0 + rg, d = w * 16 + col;
                size_t idx = ((size_t)b * 256 + n) * 128 + d;
                float v = acc[rg] + h_em[idx];
                y[idx] = v;
                s1 += v; s2 += v * v;
            }
        }
#pragma unroll
        for (int off = 32; off; off >>= 1) {
            s1 += __shfl_xor(s1, off, 64);
            s2 += __shfl_xor(s2, off, 64);
        }
        if (lane == 0) {
            atomicAdd(&statsA[b * 2 + 0], s1);
            atomicAdd(&statsA[b * 2 + 1], s2);
        }
    }
}

// K3: LN normalize (stats precomputed via atomics) -> bf16 xb
__global__ __launch_bounds__(256) void ln_norm_bf16(
    const float* __restrict__ y, const float* __restrict__ stats,
    __hip_bfloat16* __restrict__ out)
{
    int b = blockIdx.x >> 4;
    float s1 = stats[b * 2], s2 = stats[b * 2 + 1];
    float mean = s1 * (1.f / 32768.f);
    float var = fmaxf((s2 - s1 * mean) * (1.f / 32767.f), 0.f);
    float rstd = rsqrtf(var + 1e-5f);
    size_t base = (size_t)b * 32768 + (blockIdx.x & 15) * 2048 + threadIdx.x * 8;
    float4 v0 = *(const float4*)(y + base);
    float4 v1 = *(const float4*)(y + base + 4);
    bf16x8 o;
    o[0] = (__bf16)((v0.x - mean) * rstd); o[1] = (__bf16)((v0.y - mean) * rstd);
    o[2] = (__bf16)((v0.z - mean) * rstd); o[3] = (__bf16)((v0.w - mean) * rstd);
    o[4] = (__bf16)((v1.x - mean) * rstd); o[5] = (__bf16)((v1.y - mean) * rstd);
    o[6] = (__bf16)((v1.z - mean) * rstd); o[7] = (__bf16)((v1.w - mean) * rstd);
    *(bf16x8*)(out + base) = o;
}

// K5: LN normalize -> fp32 final output
__global__ __launch_bounds__(256) void ln_norm_f32(
    const float* __restrict__ y, const float* __restrict__ stats,
    float* __restrict__ out)
{
    int b = blockIdx.x >> 4;
    float s1 = stats[b * 2], s2 = stats[b * 2 + 1];
    float mean = s1 * (1.f / 32768.f);
    float var = fmaxf((s2 - s1 * mean) * (1.f / 32767.f), 0.f);
    float rstd = rsqrtf(var + 1e-5f);
    size_t base = (size_t)b * 32768 + (blockIdx.x & 15) * 2048 + threadIdx.x * 8;
    float4 v0 = *(const float4*)(y + base);
    float4 v1 = *(const float4*)(y + base + 4);
    float4 o0, o1;
    o0.x = (v0.x - mean) * rstd; o0.y = (v0.y - mean) * rstd;
    o0.z = (v0.z - mean) * rstd; o0.w = (v0.w - mean) * rstd;
    o1.x = (v1.x - mean) * rstd; o1.y = (v1.y - mean) * rstd;
    o1.z = (v1.z - mean) * rstd; o1.w = (v1.w - mean) * rstd;
    *(float4*)(out + base) = o0;
    *(float4*)(out + base + 4) = o1;
}

// K4: fused FF: y = relu(x @ w1) @ w2 + x, hidden tile in LDS; + LN2 stats
__global__ __launch_bounds__(512) void ff_kernel(
    const __hip_bfloat16* __restrict__ xb, const __hip_bfloat16* __restrict__ w1t,
    const __hip_bfloat16* __restrict__ w2t, float* __restrict__ y,
    float* __restrict__ statsB)
{
    __shared__ alignas(16) __hip_bfloat16 hid[64][512];   // 64 KB
    const int w = threadIdx.x >> 6, lane = threadIdx.x & 63;
    const int quad = lane >> 4, col = lane & 15;
    const int r0 = blockIdx.x * 64;
    const int b = blockIdx.x >> 2;

    f32x4 acc[4][4] = {};
#pragma unroll
    for (int ks = 0; ks < 4; ++ks) {
        bf16x8 a[4], bb[4];
#pragma unroll
        for (int mt = 0; mt < 4; ++mt)
            a[mt] = ld8(xb + (size_t)(r0 + mt * 16 + col) * 128 + ks * 32 + quad * 8);
#pragma unroll
        for (int nt = 0; nt < 4; ++nt) {
            int f = (w * 4 + nt) * 16 + col;
            bb[nt] = ld8(w1t + (size_t)f * 128 + ks * 32 + quad * 8);
        }
#pragma unroll
        for (int mt = 0; mt < 4; ++mt)
#pragma unroll
            for (int nt = 0; nt < 4; ++nt)
                acc[mt][nt] = mfma16(a[mt], bb[nt], acc[mt][nt]);
    }
#pragma unroll
    for (int mt = 0; mt < 4; ++mt)
#pragma unroll
        for (int nt = 0; nt < 4; ++nt)
#pragma unroll
            for (int rg = 0; rg < 4; ++rg) {
                int row = mt * 16 + quad * 4 + rg;
                int f = (w * 4 + nt) * 16 + col;
                hid[row][f] = f2bf(fmaxf(acc[mt][nt][rg], 0.f));
            }
    __syncthreads();

    f32x4 acc2[4] = {};
#pragma unroll
    for (int ks = 0; ks < 16; ++ks) {
        bf16x8 bb = ld8(w2t + (size_t)(w * 16 + col) * 512 + ks * 32 + quad * 8);
#pragma unroll
        for (int mt = 0; mt < 4; ++mt) {
            bf16x8 a = ld8(&hid[mt * 16 + col][ks * 32 + quad * 8]);
            acc2[mt] = mfma16(a, bb, acc2[mt]);
        }
    }
    float s1 = 0.f, s2 = 0.f;
#pragma unroll
    for (int mt = 0; mt < 4; ++mt)
#pragma unroll
        for (int rg = 0; rg < 4; ++rg) {
            int row = r0 + mt * 16 + quad * 4 + rg;
            int d = w * 16 + col;
            size_t idx = (size_t)row * 128 + d;
            float v = acc2[mt][rg] + bf2f(xb[idx]);
            y[idx] = v;
            s1 += v; s2 += v * v;
        }
#pragma unroll
    for (int off = 32; off; off >>= 1) {
        s1 += __shfl_xor(s1, off, 64);
        s2 += __shfl_xor(s2, off, 64);
    }
    if (lane == 0) {
        atomicAdd(&statsB[b * 2 + 0], s1);
        atomicAdd(&statsB[b * 2 + 1], s2);
    }
}

extern "C" void kernel_launch(void* const* d_in, const int* in_sizes, int n_in,
                              void* d_out, int out_size, void* d_ws, size_t ws_size,
                              hipStream_t stream)
{
    const float* h_em  = (const float*)d_in[0];
    const float* route = (const float*)d_in[1];
    const float* Wq    = (const float*)d_in[2];
    const float* Wk    = (const float*)d_in[3];
    const float* Wv    = (const float*)d_in[4];
    const float* W_out = (const float*)d_in[5];
    const float* sa_w1 = (const float*)d_in[6];
    const float* sa_b1 = (const float*)d_in[7];
    const float* sa_w2 = (const float*)d_in[8];
    const float* sa_b2 = (const float*)d_in[9];
    const float* ff_w1 = (const float*)d_in[10];
    const float* ff_w2 = (const float*)d_in[11];

    char* ws = (char*)d_ws;
    __hip_bfloat16* Qb    = (__hip_bfloat16*)(ws);
    __hip_bfloat16* Kb    = (__hip_bfloat16*)(ws + 4194304);
    __hip_bfloat16* Vtb   = (__hip_bfloat16*)(ws + 8388608);
    __hip_bfloat16* Wqkvt = (__hip_bfloat16*)(ws + 12582912);
    __hip_bfloat16* Wot   = (__hip_bfloat16*)(ws + 12681216);
    __hip_bfloat16* w1t   = (__hip_bfloat16*)(ws + 12713984);
    __hip_bfloat16* w2t   = (__hip_bfloat16*)(ws + 12845056);
    float*          yv    = (float*)(ws + 12976128);
    __hip_bfloat16* xb    = (__hip_bfloat16*)(ws + 21364736);
    float*          stats = (float*)(ws + 25559040);   // [256]: A=0..127, B=128..255
    float*          statsA = stats;
    float*          statsB = stats + 128;

    hipLaunchKernelGGL(repack_kernel, dim3(768), dim3(256), 0, stream,
                       Wq, Wk, Wv, W_out, ff_w1, ff_w2, Wqkvt, Wot, w1t, w2t, stats);
    hipLaunchKernelGGL(qkv_kernel, dim3(512), dim3(512), 0, stream,
                       h_em, Wqkvt, Qb, Kb, Vtb);
    hipLaunchKernelGGL(attn_kernel_v2, dim3(4096), dim3(512), 0, stream,
                       Qb, Kb, Vtb, route, sa_w1, sa_b1, sa_w2, sa_b2, h_em, Wot,
                       yv, (float*)d_out, statsA);
    hipLaunchKernelGGL(ln_norm_bf16, dim3(1024), dim3(256), 0, stream, yv, statsA, xb);
    hipLaunchKernelGGL(ff_kernel, dim3(256), dim3(512), 0, stream, xb, w1t, w2t, yv, statsB);
    hipLaunchKernelGGL(ln_norm_f32, dim3(1024), dim3(256), 0, stream, yv, statsB, (float*)d_out);
}